// Round 11
// baseline (27126.956 us; speedup 1.0000x reference)
//
#include <hip/hip_runtime.h>

// Problem constants
#define LSEQ 2048
#define HID  512
#define EMB  256
#define KD   768
// Structure: 8 independent n-groups (16 batch rows). Group = 16 blocks x 32 h.
// Block = 8 waves; wave = ONE 16x16 M-tile with rows ordered h_local*4+gate,
// full K=768 (24 K-tiles of 32). All gates of an (n,h) land in one lane's acc.
// NO LDS, NO __syncthreads in the loop: per-wave flags only.
#define NGRP 8
#define NPG  16
#define HBLK 16
#define HPB  32
#define NWG  128
#define NTHR 512
#define RING 4

#define AT_RLX __ATOMIC_RELAXED
#define AT_REL __ATOMIC_RELEASE
#define SCOPE  __HIP_MEMORY_SCOPE_AGENT

typedef unsigned long long ull;
typedef unsigned short u16;
typedef _Float16 f16;
typedef f16   f16x8 __attribute__((ext_vector_type(8)));
typedef float f32x4 __attribute__((ext_vector_type(4)));

__device__ __forceinline__ float sigf(float x) { return 1.0f / (1.0f + __expf(-x)); }
__device__ __forceinline__ float tanhfast(float x) { return fmaf(-2.0f, 1.0f / (1.0f + __expf(2.0f * x)), 1.0f); }

__global__ void __launch_bounds__(NTHR, 2)
lstm_pers(const int* __restrict__ X, const float* __restrict__ E,
          const float* __restrict__ Ww, const float* __restrict__ Wb,
          float* __restrict__ out, float* __restrict__ ws)
{
    const int tid  = threadIdx.x;
    const int bid  = blockIdx.x;
    const int ng   = bid & (NGRP - 1);      // n-group (bid&7: XCD-local heuristic)
    const int hb   = bid >> 3;              // h-block 0..15 within group
    const int w    = tid >> 6;              // wave 0..7
    const int lane = tid & 63;
    const int quad = lane >> 4;
    const int m16  = lane & 15;
    const int hme  = hb * HPB + w * 4 + quad;   // this lane's h (owns all 4 gates)
    const int nme  = ng * NPG + m16;            // this lane's n

    f16* Hbuf  = (f16*)ws;                                   // [grp][slot][n16][k512]
    int* flags = (int*)((char*)ws + (size_t)NGRP * RING * NPG * HID * 2); // [grp][128]

    // ---- W fragments -> VGPRs (fp16), persistent. A-row m16 = h_local*4+g:
    // h_local = m16>>2, g = m16&3. Lane holds A[m=m16][k=quad*8+j].
    f16x8 wf[24];
    {
        const float* wrow = Ww + ((size_t)(m16 & 3) * HID + hb * HPB + w * 4 + (m16 >> 2)) * KD
                               + quad * 8;
        #pragma unroll
        for (int ti = 0; ti < 24; ++ti) {
            const float* wp = wrow + ti * 32;
            f16x8 v;
            #pragma unroll
            for (int j = 0; j < 8; ++j) v[j] = (f16)wp[j];
            wf[ti] = v;
        }
    }
    float b0 = Wb[0 * HID + hme], b1 = Wb[1 * HID + hme];
    float b2 = Wb[2 * HID + hme], b3 = Wb[3 * HID + hme];
    float cst = 0.0f;                        // cell state for (nme, hme)

    // zero H(0) slot 0: each lane zeroes its own (n,h) cell; group covers all.
    __hip_atomic_store((u16*)(Hbuf + ((size_t)(ng * RING) * NPG + m16) * HID + hme),
                       (u16)0, AT_RLX, SCOPE);
#if __has_builtin(__builtin_amdgcn_s_waitcnt)
    __builtin_amdgcn_s_waitcnt(0);           // drain zero-stores to LLC
#endif
    // flags poisoned 0xAAAAAAAA (negative) -> signed compares work.
    if (lane == 0)
        __hip_atomic_store(&flags[ng * 128 + hb * 8 + w], 0, AT_RLX, SCOPE);

    const int* fp = flags + ng * 128;

    for (int t = 0; t < LSEQ; ++t) {
        // ---- E B-frags (K-tiles 16..23): cached loads, BEFORE the poll ----
        f16x8 be[8];
        {
            int xi = X[(size_t)nme * LSEQ + t];
            const float* eb = E + (size_t)xi * EMB + quad * 8;
            #pragma unroll
            for (int ti = 0; ti < 8; ++ti) {
                const float* ep = eb + ti * 32;
                f32x4 e0 = *(const f32x4*)ep;
                f32x4 e1 = *(const f32x4*)(ep + 4);
                f16x8 v;
                #pragma unroll
                for (int j = 0; j < 4; ++j) { v[j] = (f16)e0[j]; v[4 + j] = (f16)e1[j]; }
                be[ti] = v;
            }
        }
        // ---- poll all 128 producer-wave flags of this group (2 loads + __all) ----
        {
            const int* p0 = fp + lane;
            const int* p1 = fp + 64 + lane;
            while (true) {
                int f0 = __hip_atomic_load(p0, AT_RLX, SCOPE);
                int f1 = __hip_atomic_load(p1, AT_RLX, SCOPE);
                if (__all((f0 >= t) && (f1 >= t))) break;
                __builtin_amdgcn_s_sleep(1);
            }
        }
        // ---- H B-frags (K-tiles 0..15): bypass 2x8B loads, issued up-front ----
        const f16* Hc = Hbuf + (size_t)(ng * RING + (t & (RING - 1))) * NPG * HID;
        union { ull u[2]; f16x8 v; } bh[16];
        {
            const ull* hp = (const ull*)(Hc + (size_t)m16 * HID + quad * 8);
            #pragma unroll
            for (int ti = 0; ti < 16; ++ti) {
                bh[ti].u[0] = __hip_atomic_load(hp + ti * 8,     AT_RLX, SCOPE);
                bh[ti].u[1] = __hip_atomic_load(hp + ti * 8 + 1, AT_RLX, SCOPE);
            }
        }
        // ---- MFMA: E tiles first (overlap H-load latency), 2 acc chains ----
        f32x4 a0 = {0, 0, 0, 0}, a1 = {0, 0, 0, 0};
        #pragma unroll
        for (int ti = 0; ti < 8; ti += 2) {
            a0 = __builtin_amdgcn_mfma_f32_16x16x32_f16(wf[16 + ti],     be[ti],     a0, 0, 0, 0);
            a1 = __builtin_amdgcn_mfma_f32_16x16x32_f16(wf[16 + ti + 1], be[ti + 1], a1, 0, 0, 0);
        }
        #pragma unroll
        for (int ti = 0; ti < 16; ti += 2) {
            a0 = __builtin_amdgcn_mfma_f32_16x16x32_f16(wf[ti],     bh[ti].v,     a0, 0, 0, 0);
            a1 = __builtin_amdgcn_mfma_f32_16x16x32_f16(wf[ti + 1], bh[ti + 1].v, a1, 0, 0, 0);
        }
        // ---- gates: D row quad*4+r -> (h=hme, gate=r). All in this lane. ----
        float F = sigf(a0[0] + a1[0] + b0);
        float I = sigf(a0[1] + a1[1] + b1);
        float O = sigf(a0[2] + a1[2] + b2);
        float T = tanhfast(a0[3] + a1[3] + b3);
        cst = fmaf(F, cst, I * T);
        float hn = O * tanhfast(cst);
        // ---- publish: own 2B bypass store -> wave drain -> wave flag ----
        f16* Hw = Hbuf + (size_t)(ng * RING + ((t + 1) & (RING - 1))) * NPG * HID;
        union { f16 f; u16 u; } cv; cv.f = (f16)hn;
        __hip_atomic_store((u16*)(Hw + (size_t)m16 * HID + hme), cv.u, AT_RLX, SCOPE);
        if (t == LSEQ - 1)
            out[(size_t)nme * HID + hme] = hn;   // plain store: L2 flushed at kernel end
#if __has_builtin(__builtin_amdgcn_s_waitcnt)
        __builtin_amdgcn_s_waitcnt(0);           // this wave's stores ack'd at LLC
        if (lane == 0)
            __hip_atomic_store(&flags[ng * 128 + hb * 8 + w], t + 1, AT_RLX, SCOPE);
#else
        if (lane == 0)
            __hip_atomic_store(&flags[ng * 128 + hb * 8 + w], t + 1, AT_REL, SCOPE);
#endif
        // Skew bound: no wave passes poll(t+1) until ALL group waves flagged t+1,
        // so max inter-wave skew = 1 step; slot (t+1)&3 writes never collide with
        // slot t&3 reads. RING=4 > 2 needed.
    }
}

extern "C" void kernel_launch(void* const* d_in, const int* in_sizes, int n_in,
                              void* d_out, int out_size, void* d_ws, size_t ws_size,
                              hipStream_t stream) {
    const int*   X   = (const int*)d_in[0];
    const float* E   = (const float*)d_in[1];
    const float* Ww  = (const float*)d_in[2];
    const float* Wb  = (const float*)d_in[3];
    float*       out = (float*)d_out;
    float*       ws  = (float*)d_ws;
    void* args[] = { (void*)&X, (void*)&E, (void*)&Ww, (void*)&Wb, (void*)&out, (void*)&ws };
    hipError_t e = hipLaunchCooperativeKernel((const void*)lstm_pers, dim3(NWG), dim3(NTHR),
                                              args, 0, stream);
    if (e != hipSuccess) {
        // 128 blocks, 0 LDS, <=256 VGPR -> trivially co-resident on 256 CUs.
        hipLaunchKernelGGL(lstm_pers, dim3(NWG), dim3(NTHR), 0, stream,
                           X, E, Ww, Wb, out, ws);
    }
}